// Round 22
// baseline (410.261 us; speedup 1.0000x reference)
//
#include <hip/hip_runtime.h>
#include <stdint.h>

#define BB 8
#define SS 1024
#define EE 1024
#define HH 16
#define HDD 64

typedef unsigned short u16_t;
typedef __attribute__((ext_vector_type(8))) short short8;
typedef __attribute__((ext_vector_type(4))) float f32x4;

__device__ __forceinline__ u16_t f2bf(float f){
    union { float f; uint32_t u; } v; v.f = f;
    return (u16_t)((v.u + 0x7fffu + ((v.u >> 16) & 1u)) >> 16);
}
__device__ __forceinline__ float bf2f(u16_t u){
    union { uint32_t u; float f; } v; v.u = ((uint32_t)u) << 16;
    return v.f;
}

__device__ __forceinline__ void gload_lds16(const void* g, void* l){
    __builtin_amdgcn_global_load_lds((const __attribute__((address_space(1))) unsigned int*)g,
                                     (__attribute__((address_space(3))) unsigned int*)l, 16, 0, 0);
}

#define MFMA16(a,b,c) __builtin_amdgcn_mfma_f32_16x16x32_bf16(a,b,c,0,0,0)

union U8 { short8 v; u16_t u[8]; };

// ---------------- f32 -> bf16 convert, 3 arrays batched via z ----------------
__global__ __launch_bounds__(256) void cvt3_f32_bf16(const float* __restrict__ s0,
                                                     const float* __restrict__ s1,
                                                     const float* __restrict__ s2,
                                                     u16_t* __restrict__ d0,
                                                     u16_t* __restrict__ d1,
                                                     u16_t* __restrict__ d2, int n8){
    const float* in = (blockIdx.z == 0) ? s0 : (blockIdx.z == 1 ? s1 : s2);
    u16_t* out      = (blockIdx.z == 0) ? d0 : (blockIdx.z == 1 ? d1 : d2);
    int i = blockIdx.x * blockDim.x + threadIdx.x;
    int stride = gridDim.x * blockDim.x;
    for (; i < n8; i += stride){
        const float4* p = (const float4*)(in + (size_t)i * 8);
        float4 a = p[0], b = p[1];
        U8 o;
        o.u[0]=f2bf(a.x); o.u[1]=f2bf(a.y); o.u[2]=f2bf(a.z); o.u[3]=f2bf(a.w);
        o.u[4]=f2bf(b.x); o.u[5]=f2bf(b.y); o.u[6]=f2bf(b.z); o.u[7]=f2bf(b.w);
        *(short8*)(out + (size_t)i * 8) = o.v;
    }
}

// ---------------- f32 -> bf16 convert, 4 weight matrices batched via z ----------------
__global__ __launch_bounds__(256) void cvtW4_f32_bf16(const float* __restrict__ s0,
                                                      const float* __restrict__ s1,
                                                      const float* __restrict__ s2,
                                                      const float* __restrict__ s3,
                                                      u16_t* __restrict__ d0,
                                                      u16_t* __restrict__ d1,
                                                      u16_t* __restrict__ d2,
                                                      u16_t* __restrict__ d3, int n8){
    const float* in;
    u16_t* out;
    switch (blockIdx.z){
        case 0: in = s0; out = d0; break;
        case 1: in = s1; out = d1; break;
        case 2: in = s2; out = d2; break;
        default: in = s3; out = d3; break;
    }
    int i = blockIdx.x * blockDim.x + threadIdx.x;
    int stride = gridDim.x * blockDim.x;
    for (; i < n8; i += stride){
        const float4* p = (const float4*)(in + (size_t)i * 8);
        float4 a = p[0], b = p[1];
        U8 o;
        o.u[0]=f2bf(a.x); o.u[1]=f2bf(a.y); o.u[2]=f2bf(a.z); o.u[3]=f2bf(a.w);
        o.u[4]=f2bf(b.x); o.u[5]=f2bf(b.y); o.u[6]=f2bf(b.z); o.u[7]=f2bf(b.w);
        *(short8*)(out + (size_t)i * 8) = o.v;
    }
}

// ---------------- mask int32 -> bf16 bias (0 or ~-1e9) ----------------
__global__ __launch_bounds__(256) void cvt_mask(const int* __restrict__ mask,
                                                u16_t* __restrict__ mb, int n8){
    int i = blockIdx.x * blockDim.x + threadIdx.x;
    int stride = gridDim.x * blockDim.x;
    for (; i < n8; i += stride){
        const int4* p = (const int4*)(mask + (size_t)i * 8);
        int4 a = p[0], b = p[1];
        U8 o;
        o.u[0]=a.x?0xCE6Eu:0u; o.u[1]=a.y?0xCE6Eu:0u; o.u[2]=a.z?0xCE6Eu:0u; o.u[3]=a.w?0xCE6Eu:0u;
        o.u[4]=b.x?0xCE6Eu:0u; o.u[5]=b.y?0xCE6Eu:0u; o.u[6]=b.z?0xCE6Eu:0u; o.u[7]=b.w?0xCE6Eu:0u;
        *(short8*)(mb + (size_t)i * 8) = o.v;
    }
}

// ---------------- V transpose: Vp[b*S+s][h*64+d] -> Vt[(b*16+h)*64+d][s] ----------------
__global__ __launch_bounds__(256) void transpose_v(const u16_t* __restrict__ Vp,
                                                   u16_t* __restrict__ Vt){
    __shared__ u16_t sT[64 * 66];
    const int b = blockIdx.z, h = blockIdx.y, s0 = blockIdx.x * 64;
    const int tid = threadIdx.x;
    #pragma unroll
    for (int it = 0; it < 2; it++){
        int c = it * 256 + tid;
        int sr = c >> 3, c8 = c & 7;
        short8 v = *(const short8*)(Vp + (size_t)(b * SS + s0 + sr) * EE + h * HDD + c8 * 8);
        *(short8*)(sT + sr * 66 + c8 * 8) = v;
    }
    __syncthreads();
    #pragma unroll
    for (int it = 0; it < 2; it++){
        int c = it * 256 + tid;
        int dr = c >> 3, c8 = c & 7;
        U8 o;
        #pragma unroll
        for (int e = 0; e < 8; e++) o.u[e] = sT[(c8 * 8 + e) * 66 + dr];
        *(short8*)(Vt + ((size_t)(b * HH + h) * HDD + dr) * SS + s0 + c8 * 8) = o.v;
    }
}

// XCD-aware tile remap for grid (8, 64): XCD k owns M-chunk [k*8,k*8+8) x all 8 N-panels
// -> per-XCD working set 2.1MB A + 2MB B, L2-resident (A fetched once vs 8x).
__device__ __forceinline__ void xcd_tiles(int& m0, int& n0){
    int i = blockIdx.x + blockIdx.y * 8;
    int k = i & 7, q = i >> 3;
    m0 = (k * 8 + (q >> 3)) * 128;
    n0 = (q & 7) * 128;
}

// ---------------- C = A * B^T + bias for the 3 projections, batched via z ----------------
__global__ __launch_bounds__(256) void gemm_bt3(const u16_t* __restrict__ qb,
                                                const u16_t* __restrict__ kb,
                                                const u16_t* __restrict__ vb,
                                                const u16_t* __restrict__ Wqb,
                                                const u16_t* __restrict__ Wkb,
                                                const u16_t* __restrict__ Wvb,
                                                const float* __restrict__ bq,
                                                const float* __restrict__ bk,
                                                const float* __restrict__ bv,
                                                u16_t* __restrict__ Qp,
                                                u16_t* __restrict__ Kp,
                                                u16_t* __restrict__ Vp)
{
    const u16_t *A, *Bw; const float* bias; u16_t* Cout;
    switch (blockIdx.z){
        case 0:  A = qb; Bw = Wqb; bias = bq; Cout = Qp; break;
        case 1:  A = kb; Bw = Wkb; bias = bk; Cout = Kp; break;
        default: A = vb; Bw = Wvb; bias = bv; Cout = Vp; break;
    }
    const int K = EE, N = EE;

    __shared__ u16_t sA[128 * 32];
    __shared__ u16_t sB[128 * 32];
    const int tid = threadIdx.x;
    const int wave = tid >> 6, lane = tid & 63;
    int m0, n0; xcd_tiles(m0, n0);
    const int wm = (wave >> 1) * 64, wn = (wave & 1) * 64;

    f32x4 acc[4][4] = {};

    for (int k0 = 0; k0 < K; k0 += 32){
        #pragma unroll
        for (int i = 0; i < 2; i++){
            int s   = (wave * 2 + i) * 64 + lane;
            int row = s >> 2, cb = (s & 3) * 8;
            gload_lds16(A  + (size_t)(m0 + row) * K + k0 + cb, (void*)(sA + (wave * 2 + i) * 512));
            gload_lds16(Bw + (size_t)(n0 + row) * K + k0 + cb, (void*)(sB + (wave * 2 + i) * 512));
        }
        __syncthreads();

        short8 aF[4], bF[4];
        #pragma unroll
        for (int m = 0; m < 4; m++)
            aF[m] = *(const short8*)(sA + (wm + m * 16 + (lane & 15)) * 32 + (lane >> 4) * 8);
        #pragma unroll
        for (int n = 0; n < 4; n++)
            bF[n] = *(const short8*)(sB + (wn + n * 16 + (lane & 15)) * 32 + (lane >> 4) * 8);
        #pragma unroll
        for (int m = 0; m < 4; m++)
            #pragma unroll
            for (int n = 0; n < 4; n++)
                acc[m][n] = MFMA16(aF[m], bF[n], acc[m][n]);
        __syncthreads();
    }

    #pragma unroll
    for (int m = 0; m < 4; m++){
        #pragma unroll
        for (int n = 0; n < 4; n++){
            int col = n0 + wn + n * 16 + (lane & 15);
            float bvv = bias[col];
            #pragma unroll
            for (int j = 0; j < 4; j++){
                int row = m0 + wm + m * 16 + (lane >> 4) * 4 + j;
                Cout[(size_t)row * N + col] = f2bf(acc[m][n][j] + bvv);
            }
        }
    }
}

// ---------------- C[M,N] = A[M,K] * B[N,K]^T + bias ; f32 out (final projection) --------
__global__ __launch_bounds__(256) void gemm_bt_f32(const u16_t* __restrict__ A,
                                                   const u16_t* __restrict__ Bw,
                                                   const float* __restrict__ bias,
                                                   float* __restrict__ Cout,
                                                   int M, int N, int K)
{
    __shared__ u16_t sA[128 * 32];
    __shared__ u16_t sB[128 * 32];
    const int tid = threadIdx.x;
    const int wave = tid >> 6, lane = tid & 63;
    int m0, n0; xcd_tiles(m0, n0);
    const int wm = (wave >> 1) * 64, wn = (wave & 1) * 64;

    f32x4 acc[4][4] = {};

    for (int k0 = 0; k0 < K; k0 += 32){
        #pragma unroll
        for (int i = 0; i < 2; i++){
            int s   = (wave * 2 + i) * 64 + lane;
            int row = s >> 2, cb = (s & 3) * 8;
            gload_lds16(A  + (size_t)(m0 + row) * K + k0 + cb, (void*)(sA + (wave * 2 + i) * 512));
            gload_lds16(Bw + (size_t)(n0 + row) * K + k0 + cb, (void*)(sB + (wave * 2 + i) * 512));
        }
        __syncthreads();

        short8 aF[4], bF[4];
        #pragma unroll
        for (int m = 0; m < 4; m++)
            aF[m] = *(const short8*)(sA + (wm + m * 16 + (lane & 15)) * 32 + (lane >> 4) * 8);
        #pragma unroll
        for (int n = 0; n < 4; n++)
            bF[n] = *(const short8*)(sB + (wn + n * 16 + (lane & 15)) * 32 + (lane >> 4) * 8);
        #pragma unroll
        for (int m = 0; m < 4; m++)
            #pragma unroll
            for (int n = 0; n < 4; n++)
                acc[m][n] = MFMA16(aF[m], bF[n], acc[m][n]);
        __syncthreads();
    }

    #pragma unroll
    for (int m = 0; m < 4; m++){
        #pragma unroll
        for (int n = 0; n < 4; n++){
            int col = n0 + wn + n * 16 + (lane & 15);
            float bv = bias[col];
            #pragma unroll
            for (int j = 0; j < 4; j++){
                int row = m0 + wm + m * 16 + (lane >> 4) * 4 + j;
                Cout[(size_t)row * N + col] = acc[m][n][j] + bv;
            }
        }
    }
}

// ---------------- fused attention, two sweeps, 32KB flat LDS ----------------
// grid 2048 1D; decode: b = flat&7 (== XCD), i0 = ((flat>>3)&15)*64 (fastest), h outer.
// Sweep 1: 128-row K tiles ping-pong in 2x16KB -> 9 barriers, 2x work per window.
// Sweep 2: counted-vmcnt MID barrier (T4): stageVT(t) issued FIRST at TOP (oldest in the
//   wave's VMEM FIFO; the compiler's own waits before mbv/adjv uses force VT complete
//   during QK compute for free), stageK(t+1) issued LAST after QK+exp behind a
//   sched_barrier (youngest). MID = s_waitcnt vmcnt(2) + lgkmcnt(0) + RAW s_barrier --
//   K(t+1) stays in flight across the barrier and drains at the next TOP __syncthreads
//   with the full PV+store phase as cover. t=15 uses vmcnt(0) (no prefetch -> safe).
// (256,3) = 84-VGPR no-spill corridor.
__global__ __launch_bounds__(256, 3) void attn_fused(const u16_t* __restrict__ Qp,
                                                     const u16_t* __restrict__ Kp,
                                                     const u16_t* __restrict__ Vt,
                                                     const u16_t* __restrict__ maskb,
                                                     const float* __restrict__ adjoin,
                                                     float* __restrict__ attn,
                                                     u16_t* __restrict__ X)
{
    __shared__ u16_t sL[16384];        // 32 KB flat
    u16_t* sVT = sL + 8192;            // 8 KB (sweep 2)
    u16_t* sPB = sL + 12288;           // 8 KB (Q staging, then P tiles)

    const int flat = blockIdx.x;
    const int b  = flat & 7;
    const int i0 = ((flat >> 3) & 15) * 64;
    const int h  = flat >> 7;
    const int tid = threadIdx.x, wave = tid >> 6, lane = tid & 63;
    const int frow = lane & 15, fks = lane >> 4;
    const int bh = b * HH + h;

    // ---- stage Q tile (swizzled) into sPB, extract fragments
    #pragma unroll
    for (int i = 0; i < 2; i++){
        int chunk = (wave * 2 + i) * 64 + lane;
        int row = chunk >> 3, slot = chunk & 7;
        gload_lds16(Qp + (size_t)(b * SS + i0 + row) * EE + h * HDD + (slot ^ (row & 7)) * 8,
                    (void*)(sPB + (wave * 2 + i) * 512));
    }
    __syncthreads();
    short8 aQ0, aQ1;
    {
        int row = wave * 16 + frow;
        aQ0 = *(const short8*)((const char*)sPB + row * 128 + ((fks * 16)      ^ ((row & 7) << 4)));
        aQ1 = *(const short8*)((const char*)sPB + row * 128 + ((64 + fks * 16) ^ ((row & 7) << 4)));
    }
    __syncthreads();

    auto stageK64 = [&](int j0, u16_t* dst){
        #pragma unroll
        for (int i = 0; i < 2; i++){
            int chunk = (wave * 2 + i) * 64 + lane;
            int row = chunk >> 3, slot = chunk & 7;
            gload_lds16(Kp + (size_t)(b * SS + j0 + row) * EE + h * HDD + (slot ^ (row & 7)) * 8,
                        (void*)(dst + (wave * 2 + i) * 512));
        }
    };
    auto stageK128 = [&](int j0, u16_t* dst){
        #pragma unroll
        for (int i = 0; i < 4; i++){
            int chunk = (wave * 4 + i) * 64 + lane;
            int row = chunk >> 3, slot = chunk & 7;
            gload_lds16(Kp + (size_t)(b * SS + j0 + row) * EE + h * HDD + (slot ^ (row & 7)) * 8,
                        (void*)(dst + (wave * 4 + i) * 512));
        }
    };
    auto stageVT = [&](int j0){
        #pragma unroll
        for (int i = 0; i < 2; i++){
            int chunk = (wave * 2 + i) * 64 + lane;
            int row = chunk >> 3, slot = chunk & 7;
            gload_lds16(Vt + ((size_t)bh * HDD + row) * SS + j0 + (slot ^ (row & 7)) * 8,
                        (void*)(sVT + (wave * 2 + i) * 512));
        }
    };

    const int grow0 = i0 + wave * 16 + fks * 4;
    const size_t mrowbase = (size_t)(b * SS + grow0) * SS;   // + r*SS + col

    // ========= sweep 1: rowsums of exp; 128-row K tiles ping-pong in 2x16KB =========
    float s_run[4] = {0.f, 0.f, 0.f, 0.f};
    {
        u16_t* bufs[2] = { sL, sL + 8192 };
        stageK128(0, bufs[0]);
        #pragma unroll
        for (int T = 0; T < 8; T++){
            u16_t* cur = bufs[T & 1];
            __syncthreads();                   // stage(T) arrived; prev reads done
            if (T < 7) stageK128((T + 1) * 128, bufs[(T + 1) & 1]);
            #pragma unroll
            for (int half = 0; half < 2; half++){
                const int t64 = T * 128 + half * 64;
                float mbv[4][4];
                #pragma unroll
                for (int n = 0; n < 4; n++)
                    #pragma unroll
                    for (int r = 0; r < 4; r++)
                        mbv[n][r] = bf2f(maskb[mrowbase + (size_t)r * SS + t64 + n * 16 + frow]);
                __builtin_amdgcn_s_setprio(1);
                #pragma unroll
                for (int n = 0; n < 4; n++){
                    int jrow = half * 64 + n * 16 + frow;
                    f32x4 acc = {};
                    short8 bF = *(const short8*)((const char*)cur + jrow * 128 + ((fks * 16)      ^ ((jrow & 7) << 4)));
                    acc = MFMA16(aQ0, bF, acc);
                    bF        = *(const short8*)((const char*)cur + jrow * 128 + ((64 + fks * 16) ^ ((jrow & 7) << 4)));
                    acc = MFMA16(aQ1, bF, acc);
                    #pragma unroll
                    for (int r = 0; r < 4; r++)
                        s_run[r] += __expf(acc[r] * 0.125f + mbv[n][r]);
                }
                __builtin_amdgcn_s_setprio(0);
            }
        }
    }
    float inv[4];
    #pragma unroll
    for (int r = 0; r < 4; r++){
        float v = s_run[r];
        v += __shfl_xor(v, 1); v += __shfl_xor(v, 2); v += __shfl_xor(v, 4); v += __shfl_xor(v, 8);
        inv[r] = 1.0f / v;
    }

    // ========= sweep 2: att = exp*inv + adjoin ; PV ; attn store =========
    f32x4 accPV[4] = {};
    __syncthreads();                           // sweep-1 LDS reads done; repartition
    u16_t* sK2[2] = { sL, sL + 4096 };
    stageK64(0, sK2[0]);
    #pragma unroll
    for (int t = 0; t < 16; t++){
        const int cur = t & 1;
        __syncthreads();                       // TOP: K(t) arrived (cover = prev PV+store)
        stageVT(t * 64);                       // VT(t): oldest; forced complete by mbv waits
        float mbv[4][4], adjv[4][4];
        #pragma unroll
        for (int n = 0; n < 4; n++)
            #pragma unroll
            for (int r = 0; r < 4; r++){
                size_t off = mrowbase + (size_t)r * SS + t * 64 + n * 16 + frow;
                mbv[n][r]  = bf2f(maskb[off]);
                adjv[n][r] = adjoin[off];
            }
        __builtin_amdgcn_s_setprio(1);
        #pragma unroll
        for (int n = 0; n < 4; n++){
            int jrow = n * 16 + frow;
            f32x4 acc = {};
            short8 bF = *(const short8*)((const char*)sK2[cur] + jrow * 128 + ((fks * 16)      ^ ((jrow & 7) << 4)));
            acc = MFMA16(aQ0, bF, acc);
            bF        = *(const short8*)((const char*)sK2[cur] + jrow * 128 + ((64 + fks * 16) ^ ((jrow & 7) << 4)));
            acc = MFMA16(aQ1, bF, acc);
            #pragma unroll
            for (int r = 0; r < 4; r++){
                int irow = wave * 16 + fks * 4 + r;
                float att = __expf(acc[r] * 0.125f + mbv[n][r]) * inv[r] + adjv[n][r];
                *(u16_t*)((char*)sPB + irow * 128 + (((n * 16 + frow) * 2) ^ ((irow & 7) << 4))) = f2bf(att);
            }
        }
        __builtin_amdgcn_s_setprio(0);
        // K(t+1): issued LAST (youngest in VMEM FIFO) so the counted MID keeps it in flight
        __builtin_amdgcn_sched_barrier(0);
        if (t < 15) stageK64((t + 1) * 64, sK2[cur ^ 1]);
        // MID: counted-vmcnt barrier -- VT/P visible, K(t+1) flies across
        if (t < 15) asm volatile("s_waitcnt vmcnt(2)" ::: "memory");
        else        asm volatile("s_waitcnt vmcnt(0)" ::: "memory");
        __builtin_amdgcn_sched_barrier(0);
        asm volatile("s_waitcnt lgkmcnt(0)" ::: "memory");
        __builtin_amdgcn_s_barrier();
        __builtin_amdgcn_sched_barrier(0);
        // PV MFMA: accPV[n] += att(16i x 64j) * V^T(16d x 64j)
        __builtin_amdgcn_s_setprio(1);
        {
            int prow = wave * 16 + frow;
            short8 aP0 = *(const short8*)((const char*)sPB + prow * 128 + ((fks * 16)      ^ ((prow & 7) << 4)));
            short8 aP1 = *(const short8*)((const char*)sPB + prow * 128 + ((64 + fks * 16) ^ ((prow & 7) << 4)));
            #pragma unroll
            for (int n = 0; n < 4; n++){
                int drow = n * 16 + frow;
                short8 bV0 = *(const short8*)((const char*)sVT + drow * 128 + ((fks * 16)      ^ ((drow & 7) << 4)));
                short8 bV1 = *(const short8*)((const char*)sVT + drow * 128 + ((64 + fks * 16) ^ ((drow & 7) << 4)));
                accPV[n] = MFMA16(aP0, bV0, accPV[n]);
                accPV[n] = MFMA16(aP1, bV1, accPV[n]);
            }
        }
        __builtin_amdgcn_s_setprio(0);
        {
            int rr = tid >> 4, c4 = tid & 15;
            #pragma unroll
            for (int it = 0; it < 4; it++){
                int row = it * 16 + rr;
                uint2 pv = *(const uint2*)((const char*)sPB + row * 128 + ((c4 * 8) ^ ((row & 7) << 4)));
                float4 o;
                o.x = bf2f((u16_t)(pv.x & 0xffffu));
                o.y = bf2f((u16_t)(pv.x >> 16));
                o.z = bf2f((u16_t)(pv.y & 0xffffu));
                o.w = bf2f((u16_t)(pv.y >> 16));
                *(float4*)(attn + ((size_t)bh * SS + i0 + row) * SS + t * 64 + c4 * 4) = o;
            }
        }
    }

    // ---- X write (bf16): att@V already includes adjoin contribution
    #pragma unroll
    for (int n = 0; n < 4; n++){
        #pragma unroll
        for (int j = 0; j < 4; j++){
            int row = i0 + wave * 16 + fks * 4 + j;
            int col = h * HDD + n * 16 + frow;
            X[(size_t)(b * SS + row) * EE + col] = f2bf(accPV[n][j]);
        }
    }
}

extern "C" void kernel_launch(void* const* d_in, const int* in_sizes, int n_in,
                              void* d_out, int out_size, void* d_ws, size_t ws_size,
                              hipStream_t stream)
{
    const float* query  = (const float*)d_in[0];
    const float* key    = (const float*)d_in[1];
    const float* value  = (const float*)d_in[2];
    const int*   mask   = (const int*)  d_in[3];
    const float* adjoin = (const float*)d_in[4];
    const float* Wq = (const float*)d_in[5];
    const float* bq = (const float*)d_in[6];
    const float* Wk = (const float*)d_in[7];
    const float* bk = (const float*)d_in[8];
    const float* Wv = (const float*)d_in[9];
    const float* bv = (const float*)d_in[10];
    const float* Wo = (const float*)d_in[11];
    const float* bo = (const float*)d_in[12];

    float* out  = (float*)d_out;
    float* attn = out + (size_t)BB * SS * EE;

    const size_t nBSE = (size_t)BB * SS * EE;   // 8388608 (== B*S*S)
    const size_t nEE  = (size_t)EE * EE;        // 1048576

    u16_t* p  = (u16_t*)d_ws;
    u16_t* qb  = p; p += nBSE;
    u16_t* kb  = p; p += nBSE;
    u16_t* vb  = p; p += nBSE;
    u16_t* Qp  = p; p += nBSE;
    u16_t* Kp  = p; p += nBSE;
    u16_t* Vp  = p; p += nBSE;
    u16_t* Xa  = p; p += nBSE;
    u16_t* Wqb = p; p += nEE;
    u16_t* Wkb = p; p += nEE;
    u16_t* Wvb = p; p += nEE;
    u16_t* Wob = p; p += nEE;

    // dead-region reuse after projections: Vt <- qb, maskb <- kb
    u16_t* Vt    = qb;
    u16_t* maskb = kb;

    cvt3_f32_bf16<<<dim3(1024, 1, 3), 256, 0, stream>>>(query, key, value, qb, kb, vb, (int)(nBSE / 8));
    cvtW4_f32_bf16<<<dim3(256, 1, 4), 256, 0, stream>>>(Wq, Wk, Wv, Wo, Wqb, Wkb, Wvb, Wob, (int)(nEE / 8));

    dim3 gProj(EE / 128, (BB * SS) / 128);   // (8, 64)
    gemm_bt3<<<dim3(EE / 128, (BB * SS) / 128, 3), 256, 0, stream>>>(qb, kb, vb, Wqb, Wkb, Wvb,
                                                                     bq, bk, bv, Qp, Kp, Vp);

    dim3 gT(SS / 64, HH, BB);
    transpose_v<<<gT, 256, 0, stream>>>(Vp, Vt);
    cvt_mask<<<1024, 256, 0, stream>>>(mask, maskb, (int)(nBSE / 8));

    attn_fused<<<2048, 256, 0, stream>>>(Qp, Kp, Vt, maskb, adjoin, attn, Xa);

    gemm_bt_f32<<<gProj, 256, 0, stream>>>(Xa, Wob, bo, out, BB * SS, EE, EE);
}

// Round 23
// 397.798 us; speedup vs baseline: 1.0313x; 1.0313x over previous
//
#include <hip/hip_runtime.h>
#include <stdint.h>

#define BB 8
#define SS 1024
#define EE 1024
#define HH 16
#define HDD 64

typedef unsigned short u16_t;
typedef __attribute__((ext_vector_type(8))) short short8;
typedef __attribute__((ext_vector_type(4))) float f32x4;

__device__ __forceinline__ u16_t f2bf(float f){
    union { float f; uint32_t u; } v; v.f = f;
    return (u16_t)((v.u + 0x7fffu + ((v.u >> 16) & 1u)) >> 16);
}
__device__ __forceinline__ float bf2f(u16_t u){
    union { uint32_t u; float f; } v; v.u = ((uint32_t)u) << 16;
    return v.f;
}

__device__ __forceinline__ void gload_lds16(const void* g, void* l){
    __builtin_amdgcn_global_load_lds((const __attribute__((address_space(1))) unsigned int*)g,
                                     (__attribute__((address_space(3))) unsigned int*)l, 16, 0, 0);
}

#define MFMA16(a,b,c) __builtin_amdgcn_mfma_f32_16x16x32_bf16(a,b,c,0,0,0)

union U8 { short8 v; u16_t u[8]; };

// ---------------- f32 -> bf16 convert, 3 arrays batched via z ----------------
__global__ __launch_bounds__(256) void cvt3_f32_bf16(const float* __restrict__ s0,
                                                     const float* __restrict__ s1,
                                                     const float* __restrict__ s2,
                                                     u16_t* __restrict__ d0,
                                                     u16_t* __restrict__ d1,
                                                     u16_t* __restrict__ d2, int n8){
    const float* in = (blockIdx.z == 0) ? s0 : (blockIdx.z == 1 ? s1 : s2);
    u16_t* out      = (blockIdx.z == 0) ? d0 : (blockIdx.z == 1 ? d1 : d2);
    int i = blockIdx.x * blockDim.x + threadIdx.x;
    int stride = gridDim.x * blockDim.x;
    for (; i < n8; i += stride){
        const float4* p = (const float4*)(in + (size_t)i * 8);
        float4 a = p[0], b = p[1];
        U8 o;
        o.u[0]=f2bf(a.x); o.u[1]=f2bf(a.y); o.u[2]=f2bf(a.z); o.u[3]=f2bf(a.w);
        o.u[4]=f2bf(b.x); o.u[5]=f2bf(b.y); o.u[6]=f2bf(b.z); o.u[7]=f2bf(b.w);
        *(short8*)(out + (size_t)i * 8) = o.v;
    }
}

// ---------------- f32 -> bf16 convert, 4 weight matrices batched via z ----------------
__global__ __launch_bounds__(256) void cvtW4_f32_bf16(const float* __restrict__ s0,
                                                      const float* __restrict__ s1,
                                                      const float* __restrict__ s2,
                                                      const float* __restrict__ s3,
                                                      u16_t* __restrict__ d0,
                                                      u16_t* __restrict__ d1,
                                                      u16_t* __restrict__ d2,
                                                      u16_t* __restrict__ d3, int n8){
    const float* in;
    u16_t* out;
    switch (blockIdx.z){
        case 0: in = s0; out = d0; break;
        case 1: in = s1; out = d1; break;
        case 2: in = s2; out = d2; break;
        default: in = s3; out = d3; break;
    }
    int i = blockIdx.x * blockDim.x + threadIdx.x;
    int stride = gridDim.x * blockDim.x;
    for (; i < n8; i += stride){
        const float4* p = (const float4*)(in + (size_t)i * 8);
        float4 a = p[0], b = p[1];
        U8 o;
        o.u[0]=f2bf(a.x); o.u[1]=f2bf(a.y); o.u[2]=f2bf(a.z); o.u[3]=f2bf(a.w);
        o.u[4]=f2bf(b.x); o.u[5]=f2bf(b.y); o.u[6]=f2bf(b.z); o.u[7]=f2bf(b.w);
        *(short8*)(out + (size_t)i * 8) = o.v;
    }
}

// ---------------- mask int32 -> bf16 bias (0 or ~-1e9) ----------------
__global__ __launch_bounds__(256) void cvt_mask(const int* __restrict__ mask,
                                                u16_t* __restrict__ mb, int n8){
    int i = blockIdx.x * blockDim.x + threadIdx.x;
    int stride = gridDim.x * blockDim.x;
    for (; i < n8; i += stride){
        const int4* p = (const int4*)(mask + (size_t)i * 8);
        int4 a = p[0], b = p[1];
        U8 o;
        o.u[0]=a.x?0xCE6Eu:0u; o.u[1]=a.y?0xCE6Eu:0u; o.u[2]=a.z?0xCE6Eu:0u; o.u[3]=a.w?0xCE6Eu:0u;
        o.u[4]=b.x?0xCE6Eu:0u; o.u[5]=b.y?0xCE6Eu:0u; o.u[6]=b.z?0xCE6Eu:0u; o.u[7]=b.w?0xCE6Eu:0u;
        *(short8*)(mb + (size_t)i * 8) = o.v;
    }
}

// ---------------- V transpose: Vp[b*S+s][h*64+d] -> Vt[(b*16+h)*64+d][s] ----------------
__global__ __launch_bounds__(256) void transpose_v(const u16_t* __restrict__ Vp,
                                                   u16_t* __restrict__ Vt){
    __shared__ u16_t sT[64 * 66];
    const int b = blockIdx.z, h = blockIdx.y, s0 = blockIdx.x * 64;
    const int tid = threadIdx.x;
    #pragma unroll
    for (int it = 0; it < 2; it++){
        int c = it * 256 + tid;
        int sr = c >> 3, c8 = c & 7;
        short8 v = *(const short8*)(Vp + (size_t)(b * SS + s0 + sr) * EE + h * HDD + c8 * 8);
        *(short8*)(sT + sr * 66 + c8 * 8) = v;
    }
    __syncthreads();
    #pragma unroll
    for (int it = 0; it < 2; it++){
        int c = it * 256 + tid;
        int dr = c >> 3, c8 = c & 7;
        U8 o;
        #pragma unroll
        for (int e = 0; e < 8; e++) o.u[e] = sT[(c8 * 8 + e) * 66 + dr];
        *(short8*)(Vt + ((size_t)(b * HH + h) * HDD + dr) * SS + s0 + c8 * 8) = o.v;
    }
}

// XCD-aware tile remap for grid (8, 64): XCD k owns M-chunk [k*8,k*8+8) x all 8 N-panels
// -> per-XCD working set 2.1MB A + 2MB B, L2-resident (A fetched once vs 8x).
__device__ __forceinline__ void xcd_tiles(int& m0, int& n0){
    int i = blockIdx.x + blockIdx.y * 8;
    int k = i & 7, q = i >> 3;
    m0 = (k * 8 + (q >> 3)) * 128;
    n0 = (q & 7) * 128;
}

// ---------------- C = A * B^T + bias for the 3 projections, batched via z ----------------
__global__ __launch_bounds__(256) void gemm_bt3(const u16_t* __restrict__ qb,
                                                const u16_t* __restrict__ kb,
                                                const u16_t* __restrict__ vb,
                                                const u16_t* __restrict__ Wqb,
                                                const u16_t* __restrict__ Wkb,
                                                const u16_t* __restrict__ Wvb,
                                                const float* __restrict__ bq,
                                                const float* __restrict__ bk,
                                                const float* __restrict__ bv,
                                                u16_t* __restrict__ Qp,
                                                u16_t* __restrict__ Kp,
                                                u16_t* __restrict__ Vp)
{
    const u16_t *A, *Bw; const float* bias; u16_t* Cout;
    switch (blockIdx.z){
        case 0:  A = qb; Bw = Wqb; bias = bq; Cout = Qp; break;
        case 1:  A = kb; Bw = Wkb; bias = bk; Cout = Kp; break;
        default: A = vb; Bw = Wvb; bias = bv; Cout = Vp; break;
    }
    const int K = EE, N = EE;

    __shared__ u16_t sA[128 * 32];
    __shared__ u16_t sB[128 * 32];
    const int tid = threadIdx.x;
    const int wave = tid >> 6, lane = tid & 63;
    int m0, n0; xcd_tiles(m0, n0);
    const int wm = (wave >> 1) * 64, wn = (wave & 1) * 64;

    f32x4 acc[4][4] = {};

    for (int k0 = 0; k0 < K; k0 += 32){
        #pragma unroll
        for (int i = 0; i < 2; i++){
            int s   = (wave * 2 + i) * 64 + lane;
            int row = s >> 2, cb = (s & 3) * 8;
            gload_lds16(A  + (size_t)(m0 + row) * K + k0 + cb, (void*)(sA + (wave * 2 + i) * 512));
            gload_lds16(Bw + (size_t)(n0 + row) * K + k0 + cb, (void*)(sB + (wave * 2 + i) * 512));
        }
        __syncthreads();

        short8 aF[4], bF[4];
        #pragma unroll
        for (int m = 0; m < 4; m++)
            aF[m] = *(const short8*)(sA + (wm + m * 16 + (lane & 15)) * 32 + (lane >> 4) * 8);
        #pragma unroll
        for (int n = 0; n < 4; n++)
            bF[n] = *(const short8*)(sB + (wn + n * 16 + (lane & 15)) * 32 + (lane >> 4) * 8);
        #pragma unroll
        for (int m = 0; m < 4; m++)
            #pragma unroll
            for (int n = 0; n < 4; n++)
                acc[m][n] = MFMA16(aF[m], bF[n], acc[m][n]);
        __syncthreads();
    }

    #pragma unroll
    for (int m = 0; m < 4; m++){
        #pragma unroll
        for (int n = 0; n < 4; n++){
            int col = n0 + wn + n * 16 + (lane & 15);
            float bvv = bias[col];
            #pragma unroll
            for (int j = 0; j < 4; j++){
                int row = m0 + wm + m * 16 + (lane >> 4) * 4 + j;
                Cout[(size_t)row * N + col] = f2bf(acc[m][n][j] + bvv);
            }
        }
    }
}

// ---------------- C[M,N] = A[M,K] * B[N,K]^T + bias ; f32 out (final projection) --------
__global__ __launch_bounds__(256) void gemm_bt_f32(const u16_t* __restrict__ A,
                                                   const u16_t* __restrict__ Bw,
                                                   const float* __restrict__ bias,
                                                   float* __restrict__ Cout,
                                                   int M, int N, int K)
{
    __shared__ u16_t sA[128 * 32];
    __shared__ u16_t sB[128 * 32];
    const int tid = threadIdx.x;
    const int wave = tid >> 6, lane = tid & 63;
    int m0, n0; xcd_tiles(m0, n0);
    const int wm = (wave >> 1) * 64, wn = (wave & 1) * 64;

    f32x4 acc[4][4] = {};

    for (int k0 = 0; k0 < K; k0 += 32){
        #pragma unroll
        for (int i = 0; i < 2; i++){
            int s   = (wave * 2 + i) * 64 + lane;
            int row = s >> 2, cb = (s & 3) * 8;
            gload_lds16(A  + (size_t)(m0 + row) * K + k0 + cb, (void*)(sA + (wave * 2 + i) * 512));
            gload_lds16(Bw + (size_t)(n0 + row) * K + k0 + cb, (void*)(sB + (wave * 2 + i) * 512));
        }
        __syncthreads();

        short8 aF[4], bF[4];
        #pragma unroll
        for (int m = 0; m < 4; m++)
            aF[m] = *(const short8*)(sA + (wm + m * 16 + (lane & 15)) * 32 + (lane >> 4) * 8);
        #pragma unroll
        for (int n = 0; n < 4; n++)
            bF[n] = *(const short8*)(sB + (wn + n * 16 + (lane & 15)) * 32 + (lane >> 4) * 8);
        #pragma unroll
        for (int m = 0; m < 4; m++)
            #pragma unroll
            for (int n = 0; n < 4; n++)
                acc[m][n] = MFMA16(aF[m], bF[n], acc[m][n]);
        __syncthreads();
    }

    #pragma unroll
    for (int m = 0; m < 4; m++){
        #pragma unroll
        for (int n = 0; n < 4; n++){
            int col = n0 + wn + n * 16 + (lane & 15);
            float bv = bias[col];
            #pragma unroll
            for (int j = 0; j < 4; j++){
                int row = m0 + wm + m * 16 + (lane >> 4) * 4 + j;
                Cout[(size_t)row * N + col] = acc[m][n][j] + bv;
            }
        }
    }
}

// ---------------- fused attention, two sweeps, 48KB flat LDS ----------------
// grid 2048 1D; decode: b = flat&7 (== XCD), i0 = ((flat>>3)&15)*64 (fastest), h outer.
// BOTH sweeps batched to 128 j-cols per barrier window (sweep-1 batching gave -83us):
//   sweep 1: 128-row K tiles ping-pong in 2x16KB -> 9 barriers.
//   sweep 2: 8 windows x 2 barriers (TOP, MID) instead of 16 x 2. Per window:
//     TOP (K(T) arrived) -> stageVT(T) both halves (cover = QK phase) -> QK both halves
//     -> MID (P visible; K region reads done by all waves) -> stageK(T+1) both halves
//     (cover = PV + stores, 16 MFMA + 8 float4/thread) -> PV both halves -> stores.
//   LDS: K 2x8KB + VT 2x8KB + P 2x8KB = 48KB -> 3 blocks/CU (same as champion).
//   Per-half mbv/adjv declared inside the half loop (sweep-1's register-safe pattern).
// (256,3) = 84-VGPR no-spill corridor.
__global__ __launch_bounds__(256, 3) void attn_fused(const u16_t* __restrict__ Qp,
                                                     const u16_t* __restrict__ Kp,
                                                     const u16_t* __restrict__ Vt,
                                                     const u16_t* __restrict__ maskb,
                                                     const float* __restrict__ adjoin,
                                                     float* __restrict__ attn,
                                                     u16_t* __restrict__ X)
{
    __shared__ u16_t sL[24576];        // 48 KB flat
    u16_t* sK0  = sL;
    u16_t* sK1  = sL + 4096;
    u16_t* sVT0 = sL + 8192;
    u16_t* sVT1 = sL + 12288;
    u16_t* sPB0 = sL + 16384;          // also Q staging
    u16_t* sPB1 = sL + 20480;

    const int flat = blockIdx.x;
    const int b  = flat & 7;
    const int i0 = ((flat >> 3) & 15) * 64;
    const int h  = flat >> 7;
    const int tid = threadIdx.x, wave = tid >> 6, lane = tid & 63;
    const int frow = lane & 15, fks = lane >> 4;
    const int bh = b * HH + h;

    // ---- stage Q tile (swizzled) into sPB0, extract fragments
    #pragma unroll
    for (int i = 0; i < 2; i++){
        int chunk = (wave * 2 + i) * 64 + lane;
        int row = chunk >> 3, slot = chunk & 7;
        gload_lds16(Qp + (size_t)(b * SS + i0 + row) * EE + h * HDD + (slot ^ (row & 7)) * 8,
                    (void*)(sPB0 + (wave * 2 + i) * 512));
    }
    __syncthreads();
    short8 aQ0, aQ1;
    {
        int row = wave * 16 + frow;
        aQ0 = *(const short8*)((const char*)sPB0 + row * 128 + ((fks * 16)      ^ ((row & 7) << 4)));
        aQ1 = *(const short8*)((const char*)sPB0 + row * 128 + ((64 + fks * 16) ^ ((row & 7) << 4)));
    }
    __syncthreads();

    auto stageK64 = [&](int j0, u16_t* dst){
        #pragma unroll
        for (int i = 0; i < 2; i++){
            int chunk = (wave * 2 + i) * 64 + lane;
            int row = chunk >> 3, slot = chunk & 7;
            gload_lds16(Kp + (size_t)(b * SS + j0 + row) * EE + h * HDD + (slot ^ (row & 7)) * 8,
                        (void*)(dst + (wave * 2 + i) * 512));
        }
    };
    auto stageK128 = [&](int j0, u16_t* dst){
        #pragma unroll
        for (int i = 0; i < 4; i++){
            int chunk = (wave * 4 + i) * 64 + lane;
            int row = chunk >> 3, slot = chunk & 7;
            gload_lds16(Kp + (size_t)(b * SS + j0 + row) * EE + h * HDD + (slot ^ (row & 7)) * 8,
                        (void*)(dst + (wave * 4 + i) * 512));
        }
    };
    auto stageVT64 = [&](int j0, u16_t* dst){
        #pragma unroll
        for (int i = 0; i < 2; i++){
            int chunk = (wave * 2 + i) * 64 + lane;
            int row = chunk >> 3, slot = chunk & 7;
            gload_lds16(Vt + ((size_t)bh * HDD + row) * SS + j0 + (slot ^ (row & 7)) * 8,
                        (void*)(dst + (wave * 2 + i) * 512));
        }
    };

    const int grow0 = i0 + wave * 16 + fks * 4;
    const size_t mrowbase = (size_t)(b * SS + grow0) * SS;   // + r*SS + col

    // ========= sweep 1: rowsums of exp; 128-row K tiles ping-pong in 2x16KB =========
    float s_run[4] = {0.f, 0.f, 0.f, 0.f};
    {
        u16_t* bufs[2] = { sL, sL + 8192 };
        stageK128(0, bufs[0]);
        #pragma unroll
        for (int T = 0; T < 8; T++){
            u16_t* cur = bufs[T & 1];
            __syncthreads();                   // stage(T) arrived; prev reads done
            if (T < 7) stageK128((T + 1) * 128, bufs[(T + 1) & 1]);
            #pragma unroll
            for (int half = 0; half < 2; half++){
                const int t64 = T * 128 + half * 64;
                float mbv[4][4];
                #pragma unroll
                for (int n = 0; n < 4; n++)
                    #pragma unroll
                    for (int r = 0; r < 4; r++)
                        mbv[n][r] = bf2f(maskb[mrowbase + (size_t)r * SS + t64 + n * 16 + frow]);
                __builtin_amdgcn_s_setprio(1);
                #pragma unroll
                for (int n = 0; n < 4; n++){
                    int jrow = half * 64 + n * 16 + frow;
                    f32x4 acc = {};
                    short8 bF = *(const short8*)((const char*)cur + jrow * 128 + ((fks * 16)      ^ ((jrow & 7) << 4)));
                    acc = MFMA16(aQ0, bF, acc);
                    bF        = *(const short8*)((const char*)cur + jrow * 128 + ((64 + fks * 16) ^ ((jrow & 7) << 4)));
                    acc = MFMA16(aQ1, bF, acc);
                    #pragma unroll
                    for (int r = 0; r < 4; r++)
                        s_run[r] += __expf(acc[r] * 0.125f + mbv[n][r]);
                }
                __builtin_amdgcn_s_setprio(0);
            }
        }
    }
    float inv[4];
    #pragma unroll
    for (int r = 0; r < 4; r++){
        float v = s_run[r];
        v += __shfl_xor(v, 1); v += __shfl_xor(v, 2); v += __shfl_xor(v, 4); v += __shfl_xor(v, 8);
        inv[r] = 1.0f / v;
    }

    // ========= sweep 2: 8 windows of 128 j-cols, 2 barriers each =========
    f32x4 accPV[4] = {};
    __syncthreads();                           // sweep-1 LDS reads done; repartition
    stageK64(0, sK0); stageK64(64, sK1);       // window 0 K (cover: inv reduction, one-time)
    #pragma unroll
    for (int T = 0; T < 8; T++){
        __syncthreads();                       // TOP: K(T) arrived; prev VT/P reads done
        stageVT64(T * 128, sVT0);              // cover = QK phase (16 MFMA + 32 exp)
        stageVT64(T * 128 + 64, sVT1);
        // QK both halves -> P tiles
        #pragma unroll
        for (int half = 0; half < 2; half++){
            const u16_t* sKh = half ? sK1 : sK0;
            u16_t* sPh = half ? sPB1 : sPB0;
            const int t64 = T * 128 + half * 64;
            float mbv[4][4], adjv[4][4];
            #pragma unroll
            for (int n = 0; n < 4; n++)
                #pragma unroll
                for (int r = 0; r < 4; r++){
                    size_t off = mrowbase + (size_t)r * SS + t64 + n * 16 + frow;
                    mbv[n][r]  = bf2f(maskb[off]);
                    adjv[n][r] = adjoin[off];
                }
            __builtin_amdgcn_s_setprio(1);
            #pragma unroll
            for (int n = 0; n < 4; n++){
                int jrow = n * 16 + frow;
                f32x4 acc = {};
                short8 bF = *(const short8*)((const char*)sKh + jrow * 128 + ((fks * 16)      ^ ((jrow & 7) << 4)));
                acc = MFMA16(aQ0, bF, acc);
                bF        = *(const short8*)((const char*)sKh + jrow * 128 + ((64 + fks * 16) ^ ((jrow & 7) << 4)));
                acc = MFMA16(aQ1, bF, acc);
                #pragma unroll
                for (int r = 0; r < 4; r++){
                    int irow = wave * 16 + fks * 4 + r;
                    float att = __expf(acc[r] * 0.125f + mbv[n][r]) * inv[r] + adjv[n][r];
                    *(u16_t*)((char*)sPh + irow * 128 + (((n * 16 + frow) * 2) ^ ((irow & 7) << 4))) = f2bf(att);
                }
            }
            __builtin_amdgcn_s_setprio(0);
        }
        __syncthreads();                       // MID: VT(T) arrived; P visible; K reads done
        if (T < 7){ stageK64((T + 1) * 128, sK0); stageK64((T + 1) * 128 + 64, sK1); }
        // PV both halves (cover for K(T+1) = this phase + stores)
        __builtin_amdgcn_s_setprio(1);
        #pragma unroll
        for (int half = 0; half < 2; half++){
            const u16_t* sVh = half ? sVT1 : sVT0;
            const u16_t* sPh = half ? sPB1 : sPB0;
            int prow = wave * 16 + frow;
            short8 aP0 = *(const short8*)((const char*)sPh + prow * 128 + ((fks * 16)      ^ ((prow & 7) << 4)));
            short8 aP1 = *(const short8*)((const char*)sPh + prow * 128 + ((64 + fks * 16) ^ ((prow & 7) << 4)));
            #pragma unroll
            for (int n = 0; n < 4; n++){
                int drow = n * 16 + frow;
                short8 bV0 = *(const short8*)((const char*)sVh + drow * 128 + ((fks * 16)      ^ ((drow & 7) << 4)));
                short8 bV1 = *(const short8*)((const char*)sVh + drow * 128 + ((64 + fks * 16) ^ ((drow & 7) << 4)));
                accPV[n] = MFMA16(aP0, bV0, accPV[n]);
                accPV[n] = MFMA16(aP1, bV1, accPV[n]);
            }
        }
        __builtin_amdgcn_s_setprio(0);
        // attn stores, both halves: 16 lanes x 16B = 256B contiguous per row
        #pragma unroll
        for (int half = 0; half < 2; half++){
            const u16_t* sPh = half ? sPB1 : sPB0;
            int rr = tid >> 4, c4 = tid & 15;
            #pragma unroll
            for (int it = 0; it < 4; it++){
                int row = it * 16 + rr;
                uint2 pv = *(const uint2*)((const char*)sPh + row * 128 + ((c4 * 8) ^ ((row & 7) << 4)));
                float4 o;
                o.x = bf2f((u16_t)(pv.x & 0xffffu));
                o.y = bf2f((u16_t)(pv.x >> 16));
                o.z = bf2f((u16_t)(pv.y & 0xffffu));
                o.w = bf2f((u16_t)(pv.y >> 16));
                *(float4*)(attn + ((size_t)bh * SS + i0 + row) * SS + T * 128 + half * 64 + c4 * 4) = o;
            }
        }
    }

    // ---- X write (bf16): att@V already includes adjoin contribution
    #pragma unroll
    for (int n = 0; n < 4; n++){
        #pragma unroll
        for (int j = 0; j < 4; j++){
            int row = i0 + wave * 16 + fks * 4 + j;
            int col = h * HDD + n * 16 + frow;
            X[(size_t)(b * SS + row) * EE + col] = f2bf(accPV[n][j]);
        }
    }
}

extern "C" void kernel_launch(void* const* d_in, const int* in_sizes, int n_in,
                              void* d_out, int out_size, void* d_ws, size_t ws_size,
                              hipStream_t stream)
{
    const float* query  = (const float*)d_in[0];
    const float* key    = (const float*)d_in[1];
    const float* value  = (const float*)d_in[2];
    const int*   mask   = (const int*)  d_in[3];
    const float* adjoin = (const float*)d_in[4];
    const float* Wq = (const float*)d_in[5];
    const float* bq = (const float*)d_in[6];
    const float* Wk = (const float*)d_in[7];
    const float* bk = (const float*)d_in[8];
    const float* Wv = (const float*)d_in[9];
    const float* bv = (const float*)d_in[10];
    const float* Wo = (const float*)d_in[11];
    const float* bo = (const float*)d_in[12];

    float* out  = (float*)d_out;
    float* attn = out + (size_t)BB * SS * EE;

    const size_t nBSE = (size_t)BB * SS * EE;   // 8388608 (== B*S*S)
    const size_t nEE  = (size_t)EE * EE;        // 1048576

    u16_t* p  = (u16_t*)d_ws;
    u16_t* qb  = p; p += nBSE;
    u16_t* kb  = p; p += nBSE;
    u16_t* vb  = p; p += nBSE;
    u16_t* Qp  = p; p += nBSE;
    u16_t* Kp  = p; p += nBSE;
    u16_t* Vp  = p; p += nBSE;
    u16_t* Xa  = p; p += nBSE;
    u16_t* Wqb = p; p += nEE;
    u16_t* Wkb = p; p += nEE;
    u16_t* Wvb = p; p += nEE;
    u16_t* Wob = p; p += nEE;

    // dead-region reuse after projections: Vt <- qb, maskb <- kb
    u16_t* Vt    = qb;
    u16_t* maskb = kb;

    cvt3_f32_bf16<<<dim3(1024, 1, 3), 256, 0, stream>>>(query, key, value, qb, kb, vb, (int)(nBSE / 8));
    cvtW4_f32_bf16<<<dim3(256, 1, 4), 256, 0, stream>>>(Wq, Wk, Wv, Wo, Wqb, Wkb, Wvb, Wob, (int)(nEE / 8));

    dim3 gProj(EE / 128, (BB * SS) / 128);   // (8, 64)
    gemm_bt3<<<dim3(EE / 128, (BB * SS) / 128, 3), 256, 0, stream>>>(qb, kb, vb, Wqb, Wkb, Wvb,
                                                                     bq, bk, bv, Qp, Kp, Vp);

    dim3 gT(SS / 64, HH, BB);
    transpose_v<<<gT, 256, 0, stream>>>(Vp, Vt);
    cvt_mask<<<1024, 256, 0, stream>>>(mask, maskb, (int)(nBSE / 8));

    attn_fused<<<2048, 256, 0, stream>>>(Qp, Kp, Vt, maskb, adjoin, attn, Xa);

    gemm_bt_f32<<<gProj, 256, 0, stream>>>(Xa, Wob, bo, out, BB * SS, EE, EE);
}